// Round 16
// baseline (5243.779 us; speedup 1.0000x reference)
//
#include <hip/hip_runtime.h>
#include <math.h>

typedef unsigned short u16;
typedef unsigned int   u32;
typedef unsigned long long u64;
typedef __bf16 bf16x8 __attribute__((ext_vector_type(8)));
typedef float  f32x4  __attribute__((ext_vector_type(4)));
typedef float  f32x16 __attribute__((ext_vector_type(16)));

#define BB 256
#define TT 256
#define HD 256
#define ED 128
#define DEPTH 4      /* h ring slots */
#define NE 137       /* epochs: 128 + 9 (S=2) */

/* ws layout (u32 units):
   [0, H_U32)        : h ring, packed bf16 hi|lo<<16  [10][DEPTH][256][256]
   [CTR_OFF, +512)   : 8 barrier counters (128B padded) + gen broadcast @+256
   [GRP_OFF, +640)   : 20 group counters (l*2+bt), 128B padded
   [XP_OFF, +XP_U32) : packed x  [256][256][8]
   [WT_OFF, ...)     : 32x32x16 fragment-ordered bf16 weights               */
#define H_U32   (10 * DEPTH * BB * HD)
#define CTR_OFF H_U32
#define GRP_OFF (CTR_OFF + 512)
#define XP_OFF  (GRP_OFF + 640)
#define XP_U32  (BB * TT * 8)
#define WT_OFF  (XP_OFF + XP_U32)

__constant__ size_t g_woff[10] = {0ul,589824ul,1638400ul,2686976ul,3735552ul,
                                  4784128ul,5177344ul,5439488ul,5701632ul,5963776ul};
__constant__ int g_cb[11] = {0,73728,204800,335872,466944,598016,
                             647168,679936,712704,745472,778240};

__device__ __forceinline__ u16 f2bf_hi(float f) {
    u32 u = __float_as_uint(f);
    u32 r = (u + 0x7FFFu + ((u >> 16) & 1u)) >> 16;
    return (u16)r;
}
__device__ __forceinline__ float bf2f(u16 h) { return __uint_as_float(((u32)h) << 16); }
__device__ __forceinline__ float sigmoidf_(float v) { return 1.0f / (1.0f + expf(-v)); }

__global__ __launch_bounds__(256) void zero_state(u32* wsd) {
    const int n = XP_OFF;
    for (int i = blockIdx.x * blockDim.x + threadIdx.x; i < n; i += gridDim.x * blockDim.x)
        wsd[i] = 0u;
}

__global__ __launch_bounds__(256) void conv_x(const float* __restrict__ x, u32* __restrict__ wsd) {
    u32* xp = wsd + XP_OFF;
    for (int i = blockIdx.x * blockDim.x + threadIdx.x; i < XP_U32; i += gridDim.x * blockDim.x) {
        float v = x[i];
        u16 hi = f2bf_hi(v);
        u16 lo = f2bf_hi(v - bf2f(hi));
        xp[i] = (u32)hi | ((u32)lo << 16);
    }
}

/* weights -> bf16 hi/lo, 32x32x16 A-fragment order (r11-verified mapping):
   chunk = ((jt*4 + jh*2 + p)*NK2 + s)*64 + lane ; element e:
   r31=lane&31: jloc=r31>>2, gate=r31&3; row = gate*hd + jt*16 + jh*8 + jloc;
   k = s*16 + (lane>>5)*8 + e.   (A operand: M-row = lane&31 = jloc*4+gate) */
__global__ __launch_bounds__(256) void conv_all(
    const float* __restrict__ w_ih0_1, const float* __restrict__ w_ihr_1,
    const float* __restrict__ w_hh_1,
    const float* __restrict__ w_ih0_2, const float* __restrict__ w_ihr_2,
    const float* __restrict__ w_hh_2,
    u32* __restrict__ wsd)
{
    __bf16* dst0 = (__bf16*)(wsd + WT_OFF);
    const int nch = 778240;
    for (int ci = blockIdx.x * blockDim.x + threadIdx.x; ci < nch;
         ci += gridDim.x * blockDim.x) {
        int l = 0;
        while (ci >= g_cb[l + 1]) ++l;
        int di = ci - g_cb[l];

        const int hd  = (l < 5) ? 256 : 128;
        const int din = (l == 0) ? 32 : ((l < 6) ? 256 : 128);
        const int xw  = (l == 0) ? 8 : din;
        const int Kp  = din + hd;
        const int NK2 = Kp >> 4;

        const float *wih, *whh; int wihld, whhld;
        if (l == 0)      { wih = w_ih0_1;                                whh = w_hh_1;
                           wihld = 8;   whhld = 256; }
        else if (l < 5)  { wih = w_ihr_1 + (size_t)(l - 1) * 1024 * 256; whh = w_hh_1 + (size_t)l * 1024 * 256;
                           wihld = 256; whhld = 256; }
        else if (l == 5) { wih = w_ih0_2;                                whh = w_hh_2;
                           wihld = 256; whhld = 128; }
        else             { wih = w_ihr_2 + (size_t)(l - 6) * 512 * 128;  whh = w_hh_2 + (size_t)(l - 5) * 512 * 128;
                           wihld = 128; whhld = 128; }

        int lane = di & 63;
        int rem  = di >> 6;
        int s    = rem % NK2;
        int rem2 = rem / NK2;
        int p    = rem2 & 1;
        int jh   = (rem2 >> 1) & 1;
        int jt   = rem2 >> 2;
        int r31  = lane & 31;
        int jloc = r31 >> 2, gate = r31 & 3;
        int kh   = (lane >> 5) * 8;
        int row  = gate * hd + jt * 16 + jh * 8 + jloc;

        bf16x8 o8;
        #pragma unroll
        for (int e = 0; e < 8; ++e) {
            int k = s * 16 + kh + e;
            float v = 0.0f;
            if (k < xw) v = wih[(size_t)row * wihld + k];
            else if (k >= din && k < Kp) v = whh[(size_t)row * whhld + (k - din)];
            __bf16 h = (__bf16)v;
            o8[e] = p ? (__bf16)(v - (float)h) : h;
        }
        *(bf16x8*)(dst0 + g_woff[l] + (size_t)di * 8) = o8;
    }
}

__device__ __forceinline__ void unpack8(const uint4& a, const uint4& b, bf16x8& bh, bf16x8& bl) {
    union { u32 u[4]; bf16x8 v; } H, L;
    H.u[0] = (a.x & 0xFFFFu) | (a.y << 16);
    H.u[1] = (a.z & 0xFFFFu) | (a.w << 16);
    H.u[2] = (b.x & 0xFFFFu) | (b.y << 16);
    H.u[3] = (b.z & 0xFFFFu) | (b.w << 16);
    L.u[0] = (a.x >> 16) | (a.y & 0xFFFF0000u);
    L.u[1] = (a.z >> 16) | (a.w & 0xFFFF0000u);
    L.u[2] = (b.x >> 16) | (b.y & 0xFFFF0000u);
    L.u[3] = (b.z >> 16) | (b.w & 0xFFFF0000u);
    bh = H.v; bl = L.v;
}

/* persistent S=2 epoch loop (r14 schedule); step uses 32x32x16 MFMA:
   wave = 8j x 4 gates (M=32, row=jloc*4+gate) x 32 batches; per K=16:
   2 ds_read_b128 + 3 MFMA into 2 alternating acc chains. */
template<int DIN16, int NK2, bool ISL0>
__device__ void run_persist(int l, int bid, int xcd, int jt, int bt, int hd, u32 arr7,
    int ng, u32* __restrict__ gflg,
    const float* __restrict__ bias, u32* __restrict__ hbuf, u32* __restrict__ ctr,
    const u32* __restrict__ xp, float* __restrict__ out, const u16* __restrict__ A_sh)
{
    constexpr int DIN = DIN16 * 16;
    constexpr int RS  = (NK2 < 3) ? NK2 : 3;

    const int tid  = threadIdx.x;
    const int lane = tid & 63;
    const int wv   = tid >> 6;
    const int bq   = wv >> 1;            /* 0..3 : 32-batch group */
    const int jh   = wv & 1;             /* 0..1 : 8-j half */
    const int r31  = lane & 31;
    const int hi   = lane >> 5;
    const int kh   = hi * 8;
    const int b    = bt * 128 + bq * 32 + r31;
    const int jBase = jt * 16 + jh * 8;

    const int hiOff = ((jh * 2 + 0) * NK2) * 512 + lane * 8;
    const int loOff = ((jh * 2 + 1) * NK2) * 512 + lane * 8;

    /* bias for lane's 4 (j,gate) groups: j = jBase + 2q + hi */
    float bgr[4][4];
    #pragma unroll
    for (int q = 0; q < 4; ++q)
        #pragma unroll
        for (int g = 0; g < 4; ++g)
            bgr[q][g] = bias[g * hd + jBase + 2 * q + hi];

    f32x4 cv = {0.f, 0.f, 0.f, 0.f};
    const int lm = (l > 0) ? (l - 1) : 0;

    auto STEP = [&](int t) {
        const u32* hin   = hbuf + ((size_t)lm * DEPTH + (t & 3)) * (BB * HD);
        const u32* hprev = hbuf + ((size_t)l * DEPTH + ((t - 1) & 3)) * (BB * HD);
        u32*       hout  = hbuf + ((size_t)l * DEPTH + (t & 3)) * (BB * HD);

        auto ldB = [&](int s, uint4& A, uint4& B) {
            if constexpr (ISL0) {
                if (s == 0) {
                    if (hi == 0) {
                        const uint4* p = (const uint4*)(xp + ((size_t)b * TT + t) * 8);
                        A = p[0]; B = p[1];
                    } else { A = make_uint4(0,0,0,0); B = make_uint4(0,0,0,0); }
                } else if (s == 1) {
                    A = make_uint4(0,0,0,0); B = make_uint4(0,0,0,0);
                } else {
                    const u32* p = hprev + (size_t)b * HD + (s * 16 - 32) + kh;
                    A = *(const uint4*)p; B = *(const uint4*)(p + 4);
                }
            } else {
                const int k0 = s * 16 + kh;
                const u32* p = (k0 < DIN) ? (hin + (size_t)b * HD + k0)
                                          : (hprev + (size_t)b * HD + (k0 - DIN));
                A = *(const uint4*)p; B = *(const uint4*)(p + 4);
            }
        };

        f32x16 accA, accB;
        #pragma unroll
        for (int i = 0; i < 16; ++i) { accA[i] = 0.f; accB[i] = 0.f; }

        uint4 ra[RS], rb[RS];
        #pragma unroll
        for (int i = 0; i < RS; ++i) ldB(i, ra[i], rb[i]);

        #pragma unroll
        for (int s = 0; s < NK2; ++s) {
            bf16x8 bh, bl;
            unpack8(ra[s % RS], rb[s % RS], bh, bl);
            if (s + RS < NK2) ldB(s + RS, ra[s % RS], rb[s % RS]);

            bf16x8 ah = *(const bf16x8*)&A_sh[hiOff + s * 512];
            bf16x8 al = *(const bf16x8*)&A_sh[loOff + s * 512];

            if (s & 1) {
                accB = __builtin_amdgcn_mfma_f32_32x32x16_bf16(ah, bh, accB, 0, 0, 0);
                accB = __builtin_amdgcn_mfma_f32_32x32x16_bf16(ah, bl, accB, 0, 0, 0);
                accB = __builtin_amdgcn_mfma_f32_32x32x16_bf16(al, bh, accB, 0, 0, 0);
            } else {
                accA = __builtin_amdgcn_mfma_f32_32x32x16_bf16(ah, bh, accA, 0, 0, 0);
                accA = __builtin_amdgcn_mfma_f32_32x32x16_bf16(ah, bl, accA, 0, 0, 0);
                accA = __builtin_amdgcn_mfma_f32_32x32x16_bf16(al, bh, accA, 0, 0, 0);
            }
        }

        /* epilogue: reg q*4+g = gate g of j = jBase + 2q + hi (C/D layout:
           col=lane&31=batch, row=(reg&3)+8*(reg>>2)+4*hi = jloc*4+gate) */
        #pragma unroll
        for (int q = 0; q < 4; ++q) {
            float i_ = sigmoidf_(accA[q*4+0] + accB[q*4+0] + bgr[q][0]);
            float f_ = sigmoidf_(accA[q*4+1] + accB[q*4+1] + bgr[q][1]);
            float g_ = tanhf   (accA[q*4+2] + accB[q*4+2] + bgr[q][2]);
            float o_ = sigmoidf_(accA[q*4+3] + accB[q*4+3] + bgr[q][3]);
            cv[q] = fmaf(f_, cv[q], i_ * g_);
            float hv = o_ * tanhf(cv[q]);
            u16 h0 = f2bf_hi(hv);
            u32 pk = (u32)h0 | ((u32)f2bf_hi(hv - bf2f(h0)) << 16);
            const int j = jBase + 2 * q + hi;
            __hip_atomic_store(hout + (size_t)b * HD + j, pk,
                               __ATOMIC_RELAXED, __HIP_MEMORY_SCOPE_AGENT);
            if (l == 9 && t == TT - 1) out[(size_t)b * ED + j] = hv;
        }
    };

    for (int E = 0; E < NE; ++E) {
        const int t0 = 2 * (E - l);
        /* even step: inputs crossed the last global barrier */
        if (t0 >= 0 && t0 < TT) {
            STEP(t0);
            __syncthreads();   /* drain h stores (vmcnt 0) */
            if (tid == 0)
                __hip_atomic_fetch_add(gflg, 1u, __ATOMIC_RELAXED, __HIP_MEMORY_SCOPE_AGENT);
        }
        /* odd step: own-group recurrent dep -> cheap group sync (no fence) */
        const int t1 = t0 + 1;
        if (t1 >= 1 && t1 < TT) {
            if (tid == 0) {
                const u32 tg = (u32)ng * (u32)(E - l + 1);
                for (int it = 0; it < (1 << 20); ++it) {
                    if (__hip_atomic_load(gflg, __ATOMIC_RELAXED,
                                          __HIP_MEMORY_SCOPE_AGENT) >= tg) break;
                    __builtin_amdgcn_s_sleep(1);
                }
            }
            __syncthreads();
            STEP(t1);
        }

        /* ---- global barrier (r14 verbatim) ---- */
        __syncthreads();
        if (tid == 0) {
            __hip_atomic_fetch_add(&ctr[xcd * 32], 1u,
                                   __ATOMIC_RELAXED, __HIP_MEMORY_SCOPE_AGENT);
            const u32 w1 = (u32)(E + 1);
            if (bid == 0) {
                for (int it = 0; it < (1 << 22); ++it) {
                    bool ok = true;
                    #pragma unroll
                    for (int r = 0; r < 8; ++r) {
                        u32 tgt = ((r == 7) ? arr7 : 32u) * w1;
                        ok &= (__hip_atomic_load(&ctr[r * 32], __ATOMIC_RELAXED,
                                                 __HIP_MEMORY_SCOPE_AGENT) >= tgt);
                    }
                    if (ok) break;
                    __builtin_amdgcn_s_sleep(1);
                }
                __hip_atomic_store(&ctr[256], w1, __ATOMIC_RELAXED, __HIP_MEMORY_SCOPE_AGENT);
            } else {
                for (int it = 0; it < (1 << 22); ++it) {
                    if (__hip_atomic_load(&ctr[256], __ATOMIC_RELAXED,
                                          __HIP_MEMORY_SCOPE_AGENT) >= w1) break;
                    __builtin_amdgcn_s_sleep(1);
                }
            }
            __builtin_amdgcn_fence(__ATOMIC_ACQUIRE, "agent");  /* inv, no writeback */
        }
        __syncthreads();
    }
}

/* Grid 256 (16 idle), 512 thr = 8 waves (2 jh x 4 bq), block = 16j x 128b.
   bid%8 = XCD heuristic (correctness placement-agnostic):
     xcd 0-4 : layer = xcd   (16 jt x 2 bt)
     xcd 5   : layers 5,6 ; xcd 6 : layers 7,8 ; xcd 7 : layer 9 (16 blk) */
__global__ __launch_bounds__(512, 2) void lstm_persist(
    const float* __restrict__ b_1, const float* __restrict__ b_2,
    u32* __restrict__ wsd, float* __restrict__ out)
{
    __shared__ __align__(16) u16 A_sh[65536];   /* 128 KiB */

    const int bid = blockIdx.x;
    const int xcd = bid & 7, slot = bid >> 3;
    int l, jt, bt;
    if (xcd < 5)      { l = xcd;               bt = slot >> 4;        jt = slot & 15; }
    else if (xcd == 5){ l = 5 + (slot >> 4);   bt = (slot >> 3) & 1;  jt = slot & 7; }
    else if (xcd == 6){ l = 7 + (slot >> 4);   bt = (slot >> 3) & 1;  jt = slot & 7; }
    else              { if (slot >= 16) return; l = 9; bt = slot >> 3; jt = slot & 7; }

    const int hd  = (l < 5) ? 256 : 128;
    const int din = (l == 0) ? 32 : ((l < 6) ? 256 : 128);
    const int NK2 = (din + hd) >> 4;
    const float* bias = (l < 5) ? (b_1 + l * 1024) : (b_2 + (l - 5) * 512);

    u32* hbuf = wsd;
    u32* ctr  = wsd + CTR_OFF;
    u32* gflg = wsd + GRP_OFF + (size_t)(l * 2 + bt) * 32;
    const u32* xp = wsd + XP_OFF;
    const u16* wt = (const u16*)(wsd + WT_OFF);

    const int ng = (l < 5) ? 16 : 8;   /* blocks in this (l,bt) group */

    /* one-time: copy this block's 4-stream fragment slice into LDS */
    {
        const uint4* src = (const uint4*)(wt + g_woff[l] + (size_t)jt * 4 * NK2 * 512);
        uint4* dst = (uint4*)A_sh;
        const int n4 = NK2 * 256;
        for (int i = threadIdx.x; i < n4; i += 512) dst[i] = src[i];
    }
    __syncthreads();

    if (l == 0)
        run_persist<2, 18, true >(l, bid, xcd, jt, bt, hd, 16u, ng, gflg, bias, hbuf, ctr, xp, out, A_sh);
    else if (l < 5)
        run_persist<16, 32, false>(l, bid, xcd, jt, bt, hd, 16u, ng, gflg, bias, hbuf, ctr, xp, out, A_sh);
    else if (l == 5)
        run_persist<16, 24, false>(l, bid, xcd, jt, bt, hd, 16u, ng, gflg, bias, hbuf, ctr, xp, out, A_sh);
    else
        run_persist<8, 16, false>(l, bid, xcd, jt, bt, hd, 16u, ng, gflg, bias, hbuf, ctr, xp, out, A_sh);
}

extern "C" void kernel_launch(void* const* d_in, const int* in_sizes, int n_in,
                              void* d_out, int out_size, void* d_ws, size_t ws_size,
                              hipStream_t stream) {
    const float* x       = (const float*)d_in[0];
    const float* w_ih0_1 = (const float*)d_in[1];
    const float* w_ihr_1 = (const float*)d_in[2];
    const float* w_hh_1  = (const float*)d_in[3];
    const float* b_1     = (const float*)d_in[4];
    const float* w_ih0_2 = (const float*)d_in[5];
    const float* w_ihr_2 = (const float*)d_in[6];
    const float* w_hh_2  = (const float*)d_in[7];
    const float* b_2     = (const float*)d_in[8];
    u32*   wsd = (u32*)d_ws;
    float* out = (float*)d_out;

    hipLaunchKernelGGL(zero_state, dim3(1024), dim3(256), 0, stream, wsd);
    hipLaunchKernelGGL(conv_all, dim3(1024), dim3(256), 0, stream,
                       w_ih0_1, w_ihr_1, w_hh_1, w_ih0_2, w_ihr_2, w_hh_2, wsd);
    hipLaunchKernelGGL(conv_x, dim3(256), dim3(256), 0, stream, x, wsd);
    hipLaunchKernelGGL(lstm_persist, dim3(256), dim3(512), 0, stream,
                       b_1, b_2, wsd, out);
}

// Round 17
// 2890.154 us; speedup vs baseline: 1.8144x; 1.8144x over previous
//
#include <hip/hip_runtime.h>
#include <math.h>

typedef unsigned short u16;
typedef unsigned int   u32;
typedef unsigned long long u64;
typedef __bf16 bf16x8 __attribute__((ext_vector_type(8)));
typedef float  f32x4  __attribute__((ext_vector_type(4)));

#define BB 256
#define TT 256
#define HD 256
#define ED 128
#define DEPTH 8      /* h ring slots (= 2*S) */
#define NE 73        /* epochs: 64 + 9 (S=4) */

/* ws layout (u32 units). h rings are u16 arrays, hi and lo separate:
   [0, HRING)          : h-hi ring u16[10][DEPTH][256][256]
   [HRING, 2*HRING)    : h-lo ring u16[10][DEPTH][256][256]
   [CTR_OFF, +512)     : 8 barrier counters (128B padded) + gen bcast @+256
   [GRP_OFF, +640)     : 20 group counters (l*2+bt), 128B padded
   [XPH_OFF, +XP_U32)  : x-hi u16[256][256][8]
   [XPL_OFF, +XP_U32)  : x-lo u16[256][256][8]
   [WT_OFF, ...)       : fragment-ordered bf16 weights (r4-r14 proven)      */
#define HRING   (10 * DEPTH * BB * HD / 2)   /* u32 units per u16 ring */
#define CTR_OFF (2 * HRING)
#define GRP_OFF (CTR_OFF + 512)
#define XP_U32  (BB * TT * 8 / 2)
#define XPH_OFF (GRP_OFF + 640)
#define XPL_OFF (XPH_OFF + XP_U32)
#define WT_OFF  (XPL_OFF + XP_U32)

__constant__ size_t g_woff[10] = {0ul,589824ul,1638400ul,2686976ul,3735552ul,
                                  4784128ul,5177344ul,5439488ul,5701632ul,5963776ul};
__constant__ int g_cb[11] = {0,73728,204800,335872,466944,598016,
                             647168,679936,712704,745472,778240};

__device__ __forceinline__ u16 f2bf_hi(float f) {
    u32 u = __float_as_uint(f);
    u32 r = (u + 0x7FFFu + ((u >> 16) & 1u)) >> 16;
    return (u16)r;
}
__device__ __forceinline__ float bf2f(u16 h) { return __uint_as_float(((u32)h) << 16); }
__device__ __forceinline__ float sigmoidf_(float v) { return 1.0f / (1.0f + expf(-v)); }

__global__ __launch_bounds__(256) void zero_state(u32* wsd) {
    const int n = XPH_OFF;
    for (int i = blockIdx.x * blockDim.x + threadIdx.x; i < n; i += gridDim.x * blockDim.x)
        wsd[i] = 0u;
}

__global__ __launch_bounds__(256) void conv_x(const float* __restrict__ x, u32* __restrict__ wsd) {
    u16* xph = (u16*)(wsd + XPH_OFF);
    u16* xpl = (u16*)(wsd + XPL_OFF);
    const int n = BB * TT * 8;
    for (int i = blockIdx.x * blockDim.x + threadIdx.x; i < n; i += gridDim.x * blockDim.x) {
        float v = x[i];
        u16 hi = f2bf_hi(v);
        xph[i] = hi;
        xpl[i] = f2bf_hi(v - bf2f(hi));
    }
}

/* weights -> bf16 hi/lo, MFMA fragment order (identical to rounds 4-14) */
__global__ __launch_bounds__(256) void conv_all(
    const float* __restrict__ w_ih0_1, const float* __restrict__ w_ihr_1,
    const float* __restrict__ w_hh_1,
    const float* __restrict__ w_ih0_2, const float* __restrict__ w_ihr_2,
    const float* __restrict__ w_hh_2,
    u32* __restrict__ wsd)
{
    __bf16* dst0 = (__bf16*)(wsd + WT_OFF);
    const int nch = 778240;
    for (int ci = blockIdx.x * blockDim.x + threadIdx.x; ci < nch;
         ci += gridDim.x * blockDim.x) {
        int l = 0;
        while (ci >= g_cb[l + 1]) ++l;
        int di = ci - g_cb[l];

        const int hd  = (l < 5) ? 256 : 128;
        const int din = (l == 0) ? 32 : ((l < 6) ? 256 : 128);
        const int xw  = (l == 0) ? 8 : din;
        const int Kp  = din + hd;
        const int nk  = Kp >> 5;

        const float *wih, *whh; int wihld, whhld;
        if (l == 0)      { wih = w_ih0_1;                                whh = w_hh_1;
                           wihld = 8;   whhld = 256; }
        else if (l < 5)  { wih = w_ihr_1 + (size_t)(l - 1) * 1024 * 256; whh = w_hh_1 + (size_t)l * 1024 * 256;
                           wihld = 256; whhld = 256; }
        else if (l == 5) { wih = w_ih0_2;                                whh = w_hh_2;
                           wihld = 256; whhld = 128; }
        else             { wih = w_ihr_2 + (size_t)(l - 6) * 512 * 128;  whh = w_hh_2 + (size_t)(l - 5) * 512 * 128;
                           wihld = 128; whhld = 128; }

        int lane = di & 63;
        int rem  = di >> 6;
        int kt   = rem % nk;
        int rem2 = rem / nk;
        int p    = rem2 & 1;
        int g    = (rem2 >> 1) & 3;
        int jt   = rem2 >> 3;
        int r15  = lane & 15, kq = lane >> 4;
        int row  = g * hd + jt * 16 + r15;

        bf16x8 o8;
        #pragma unroll
        for (int e = 0; e < 8; ++e) {
            int k = kt * 32 + kq * 8 + e;
            float v = 0.0f;
            if (k < xw) v = wih[(size_t)row * wihld + k];
            else if (k >= din && k < Kp) v = whh[(size_t)row * whhld + (k - din)];
            __bf16 h = (__bf16)v;
            o8[e] = p ? (__bf16)(v - (float)h) : h;
        }
        *(bf16x8*)(dst0 + g_woff[l] + (size_t)di * 8) = o8;
    }
}

/* persistent S=4 epoch loop (r15-verified schedule) with r14's step body and
   split hi/lo h rings: per kt, B = 2x16B loads (no unpack VALU at all). */
template<int NKI, int NKT, bool ISL0>
__device__ void run_persist(int l, int bid, int xcd, int jt, int bt, int hd, u32 arr7,
    int ng, u32* __restrict__ gflg,
    const float* __restrict__ bias, u32* __restrict__ wsd, u32* __restrict__ ctr,
    float* __restrict__ out, const u16* __restrict__ A_sh)
{
    constexpr int DIN = NKI * 32;
    constexpr int RS  = (NKT < 4) ? NKT : 4;

    u16* hhi = (u16*)wsd;
    u16* hlo = (u16*)(wsd + HRING);
    const u16* xph = (const u16*)(wsd + XPH_OFF);
    const u16* xpl = (const u16*)(wsd + XPL_OFF);

    const int tid  = threadIdx.x;
    const int lane = tid & 63;
    const int wv   = tid >> 6;
    const int r15  = lane & 15;
    const int kqc  = lane >> 4;
    const int brow = bt * 128 + wv * 16 + r15;
    const int j0   = jt * 16 + kqc * 4;

    float bgr[4][4];
    #pragma unroll
    for (int g = 0; g < 4; ++g) {
        float4 v = *(const float4*)&bias[g * hd + j0];
        bgr[g][0] = v.x; bgr[g][1] = v.y; bgr[g][2] = v.z; bgr[g][3] = v.w;
    }

    int offH[4], offL[4];
    #pragma unroll
    for (int g = 0; g < 4; ++g) {
        offH[g] = (g * 2)     * NKT * 512 + lane * 8;
        offL[g] = (g * 2 + 1) * NKT * 512 + lane * 8;
    }

    float4 cv = make_float4(0.f, 0.f, 0.f, 0.f);
    const int lm = (l > 0) ? (l - 1) : 0;

    auto STEP = [&](int t) {
        const size_t sIn   = ((size_t)lm * DEPTH + (t & 7)) * (BB * HD);
        const size_t sPrev = ((size_t)l * DEPTH + ((t - 1) & 7)) * (BB * HD);
        const size_t sOut  = ((size_t)l * DEPTH + (t & 7)) * (BB * HD);

        auto ldB = [&](int kt, uint4& H4, uint4& L4) {
            if constexpr (ISL0) {
                if (kt == 0) {
                    if (kqc == 0) {
                        const size_t xo = ((size_t)brow * TT + t) * 8;
                        H4 = *(const uint4*)(xph + xo);
                        L4 = *(const uint4*)(xpl + xo);
                    } else { H4 = make_uint4(0,0,0,0); L4 = make_uint4(0,0,0,0); }
                } else {
                    const size_t o = sPrev + (size_t)brow * HD + (kt * 32 - 32) + kqc * 8;
                    H4 = *(const uint4*)(hhi + o);
                    L4 = *(const uint4*)(hlo + o);
                }
            } else {
                const int k0 = kt * 32 + kqc * 8;
                const size_t o = (k0 < DIN) ? (sIn + (size_t)brow * HD + k0)
                                            : (sPrev + (size_t)brow * HD + (k0 - DIN));
                H4 = *(const uint4*)(hhi + o);
                L4 = *(const uint4*)(hlo + o);
            }
        };

        f32x4 acc0 = {0.f,0.f,0.f,0.f}, acc1 = {0.f,0.f,0.f,0.f};
        f32x4 acc2 = {0.f,0.f,0.f,0.f}, acc3 = {0.f,0.f,0.f,0.f};

        uint4 ra[RS], rb[RS];
        #pragma unroll
        for (int i = 0; i < RS; ++i) ldB(i, ra[i], rb[i]);

        #pragma unroll
        for (int kt = 0; kt < NKT; ++kt) {
            union { uint4 u; bf16x8 v; } BH, BL;
            BH.u = ra[kt % RS]; BL.u = rb[kt % RS];
            bf16x8 bh = BH.v, bl = BL.v;
            if (kt + RS < NKT) ldB(kt + RS, ra[kt % RS], rb[kt % RS]);

            const int kof = kt * 512;
            bf16x8 a0h = *(const bf16x8*)&A_sh[offH[0] + kof];
            bf16x8 a1h = *(const bf16x8*)&A_sh[offH[1] + kof];
            bf16x8 a2h = *(const bf16x8*)&A_sh[offH[2] + kof];
            bf16x8 a3h = *(const bf16x8*)&A_sh[offH[3] + kof];
            bf16x8 a0l = *(const bf16x8*)&A_sh[offL[0] + kof];
            bf16x8 a1l = *(const bf16x8*)&A_sh[offL[1] + kof];
            bf16x8 a2l = *(const bf16x8*)&A_sh[offL[2] + kof];
            bf16x8 a3l = *(const bf16x8*)&A_sh[offL[3] + kof];

            acc0 = __builtin_amdgcn_mfma_f32_16x16x32_bf16(a0h, bh, acc0, 0, 0, 0);
            acc1 = __builtin_amdgcn_mfma_f32_16x16x32_bf16(a1h, bh, acc1, 0, 0, 0);
            acc2 = __builtin_amdgcn_mfma_f32_16x16x32_bf16(a2h, bh, acc2, 0, 0, 0);
            acc3 = __builtin_amdgcn_mfma_f32_16x16x32_bf16(a3h, bh, acc3, 0, 0, 0);
            acc0 = __builtin_amdgcn_mfma_f32_16x16x32_bf16(a0h, bl, acc0, 0, 0, 0);
            acc1 = __builtin_amdgcn_mfma_f32_16x16x32_bf16(a1h, bl, acc1, 0, 0, 0);
            acc2 = __builtin_amdgcn_mfma_f32_16x16x32_bf16(a2h, bl, acc2, 0, 0, 0);
            acc3 = __builtin_amdgcn_mfma_f32_16x16x32_bf16(a3h, bl, acc3, 0, 0, 0);
            acc0 = __builtin_amdgcn_mfma_f32_16x16x32_bf16(a0l, bh, acc0, 0, 0, 0);
            acc1 = __builtin_amdgcn_mfma_f32_16x16x32_bf16(a1l, bh, acc1, 0, 0, 0);
            acc2 = __builtin_amdgcn_mfma_f32_16x16x32_bf16(a2l, bh, acc2, 0, 0, 0);
            acc3 = __builtin_amdgcn_mfma_f32_16x16x32_bf16(a3l, bh, acc3, 0, 0, 0);
        }

        float4 hv;
        {
            float i_, f_, g_, o_;
            i_ = sigmoidf_(acc0[0] + bgr[0][0]); f_ = sigmoidf_(acc1[0] + bgr[1][0]);
            g_ = tanhf   (acc2[0] + bgr[2][0]); o_ = sigmoidf_(acc3[0] + bgr[3][0]);
            cv.x = fmaf(f_, cv.x, i_ * g_); hv.x = o_ * tanhf(cv.x);
            i_ = sigmoidf_(acc0[1] + bgr[0][1]); f_ = sigmoidf_(acc1[1] + bgr[1][1]);
            g_ = tanhf   (acc2[1] + bgr[2][1]); o_ = sigmoidf_(acc3[1] + bgr[3][1]);
            cv.y = fmaf(f_, cv.y, i_ * g_); hv.y = o_ * tanhf(cv.y);
            i_ = sigmoidf_(acc0[2] + bgr[0][2]); f_ = sigmoidf_(acc1[2] + bgr[1][2]);
            g_ = tanhf   (acc2[2] + bgr[2][2]); o_ = sigmoidf_(acc3[2] + bgr[3][2]);
            cv.z = fmaf(f_, cv.z, i_ * g_); hv.z = o_ * tanhf(cv.z);
            i_ = sigmoidf_(acc0[3] + bgr[0][3]); f_ = sigmoidf_(acc1[3] + bgr[1][3]);
            g_ = tanhf   (acc2[3] + bgr[2][3]); o_ = sigmoidf_(acc3[3] + bgr[3][3]);
            cv.w = fmaf(f_, cv.w, i_ * g_); hv.w = o_ * tanhf(cv.w);
        }

        u16 h0 = f2bf_hi(hv.x), h1 = f2bf_hi(hv.y), h2 = f2bf_hi(hv.z), h3 = f2bf_hi(hv.w);
        u64 hiP = (u64)h0 | ((u64)h1 << 16) | ((u64)h2 << 32) | ((u64)h3 << 48);
        u64 loP = (u64)f2bf_hi(hv.x - bf2f(h0)) |
                  ((u64)f2bf_hi(hv.y - bf2f(h1)) << 16) |
                  ((u64)f2bf_hi(hv.z - bf2f(h2)) << 32) |
                  ((u64)f2bf_hi(hv.w - bf2f(h3)) << 48);
        const size_t ho = sOut + (size_t)brow * HD + j0;
        __hip_atomic_store((u64*)(hhi + ho), hiP, __ATOMIC_RELAXED, __HIP_MEMORY_SCOPE_AGENT);
        __hip_atomic_store((u64*)(hlo + ho), loP, __ATOMIC_RELAXED, __HIP_MEMORY_SCOPE_AGENT);

        if (l == 9 && t == TT - 1)
            *(float4*)&out[(size_t)brow * ED + j0] = hv;
    };

    for (int E = 0; E < NE; ++E) {
        const int ep = E - l;
        if (ep >= 0 && ep < 64) {
            #pragma unroll 1
            for (int i = 0; i < 4; ++i) {
                const int t = 4 * ep + i;
                if (i > 0) {
                    /* group sync: group-mates' slot t-1 stores are in L3;
                       slot-disjointness (D=2S) keeps L2 reads fresh */
                    if (tid == 0) {
                        const u32 tg = (u32)ng * (u32)(3 * ep + i);
                        for (int it = 0; it < (1 << 20); ++it) {
                            if (__hip_atomic_load(gflg, __ATOMIC_RELAXED,
                                                  __HIP_MEMORY_SCOPE_AGENT) >= tg) break;
                            __builtin_amdgcn_s_sleep(1);
                        }
                    }
                    __syncthreads();
                }
                STEP(t);
                if (i < 3) {
                    __syncthreads();   /* drain h stores (vmcnt 0) */
                    if (tid == 0)
                        __hip_atomic_fetch_add(gflg, 1u, __ATOMIC_RELAXED, __HIP_MEMORY_SCOPE_AGENT);
                }
            }
        }

        /* ---- global barrier (r14 verbatim) ---- */
        __syncthreads();
        if (tid == 0) {
            __hip_atomic_fetch_add(&ctr[xcd * 32], 1u,
                                   __ATOMIC_RELAXED, __HIP_MEMORY_SCOPE_AGENT);
            const u32 w1 = (u32)(E + 1);
            if (bid == 0) {
                for (int it = 0; it < (1 << 22); ++it) {
                    bool ok = true;
                    #pragma unroll
                    for (int r = 0; r < 8; ++r) {
                        u32 tgt = ((r == 7) ? arr7 : 32u) * w1;
                        ok &= (__hip_atomic_load(&ctr[r * 32], __ATOMIC_RELAXED,
                                                 __HIP_MEMORY_SCOPE_AGENT) >= tgt);
                    }
                    if (ok) break;
                    __builtin_amdgcn_s_sleep(1);
                }
                __hip_atomic_store(&ctr[256], w1, __ATOMIC_RELAXED, __HIP_MEMORY_SCOPE_AGENT);
            } else {
                for (int it = 0; it < (1 << 22); ++it) {
                    if (__hip_atomic_load(&ctr[256], __ATOMIC_RELAXED,
                                          __HIP_MEMORY_SCOPE_AGENT) >= w1) break;
                    __builtin_amdgcn_s_sleep(1);
                }
            }
            __builtin_amdgcn_fence(__ATOMIC_ACQUIRE, "agent");  /* inv, no writeback */
        }
        __syncthreads();
    }
}

/* Grid 256 (16 idle), 512 thr = 8 waves x 16 batches (r10/r14 structure).
   bid%8 = XCD heuristic (correctness placement-agnostic):
     xcd 0-4 : layer = xcd   (16 jt x 2 bt)
     xcd 5   : layers 5,6 ; xcd 6 : layers 7,8 ; xcd 7 : layer 9 (16 blk) */
__global__ __launch_bounds__(512, 2) void lstm_persist(
    const float* __restrict__ b_1, const float* __restrict__ b_2,
    u32* __restrict__ wsd, float* __restrict__ out)
{
    __shared__ __align__(16) u16 A_sh[65536];   /* 128 KiB */

    const int bid = blockIdx.x;
    const int xcd = bid & 7, slot = bid >> 3;
    int l, jt, bt;
    if (xcd < 5)      { l = xcd;               bt = slot >> 4;        jt = slot & 15; }
    else if (xcd == 5){ l = 5 + (slot >> 4);   bt = (slot >> 3) & 1;  jt = slot & 7; }
    else if (xcd == 6){ l = 7 + (slot >> 4);   bt = (slot >> 3) & 1;  jt = slot & 7; }
    else              { if (slot >= 16) return; l = 9; bt = slot >> 3; jt = slot & 7; }

    const int hd  = (l < 5) ? 256 : 128;
    const int din = (l == 0) ? 32 : ((l < 6) ? 256 : 128);
    const int nk  = (din + hd) >> 5;
    const float* bias = (l < 5) ? (b_1 + l * 1024) : (b_2 + (l - 5) * 512);

    u32* ctr  = wsd + CTR_OFF;
    u32* gflg = wsd + GRP_OFF + (size_t)(l * 2 + bt) * 32;
    const u16* wt = (const u16*)(wsd + WT_OFF);

    const int ng = (l < 5) ? 16 : 8;   /* blocks in this (l,bt) group */

    /* one-time: copy this block's fragment-ordered weight slice into LDS */
    {
        const uint4* src = (const uint4*)(wt + g_woff[l] + (size_t)jt * 8 * nk * 512);
        uint4* dst = (uint4*)A_sh;
        const int n4 = nk * 512;
        for (int i = threadIdx.x; i < n4; i += 512) dst[i] = src[i];
    }
    __syncthreads();

    if (l == 0)
        run_persist<1, 9, true >(l, bid, xcd, jt, bt, hd, 16u, ng, gflg, bias, wsd, ctr, out, A_sh);
    else if (l < 5)
        run_persist<8, 16, false>(l, bid, xcd, jt, bt, hd, 16u, ng, gflg, bias, wsd, ctr, out, A_sh);
    else if (l == 5)
        run_persist<8, 12, false>(l, bid, xcd, jt, bt, hd, 16u, ng, gflg, bias, wsd, ctr, out, A_sh);
    else
        run_persist<4, 8, false>(l, bid, xcd, jt, bt, hd, 16u, ng, gflg, bias, wsd, ctr, out, A_sh);
}

extern "C" void kernel_launch(void* const* d_in, const int* in_sizes, int n_in,
                              void* d_out, int out_size, void* d_ws, size_t ws_size,
                              hipStream_t stream) {
    const float* x       = (const float*)d_in[0];
    const float* w_ih0_1 = (const float*)d_in[1];
    const float* w_ihr_1 = (const float*)d_in[2];
    const float* w_hh_1  = (const float*)d_in[3];
    const float* b_1     = (const float*)d_in[4];
    const float* w_ih0_2 = (const float*)d_in[5];
    const float* w_ihr_2 = (const float*)d_in[6];
    const float* w_hh_2  = (const float*)d_in[7];
    const float* b_2     = (const float*)d_in[8];
    u32*   wsd = (u32*)d_ws;
    float* out = (float*)d_out;

    hipLaunchKernelGGL(zero_state, dim3(1024), dim3(256), 0, stream, wsd);
    hipLaunchKernelGGL(conv_all, dim3(1024), dim3(256), 0, stream,
                       w_ih0_1, w_ihr_1, w_hh_1, w_ih0_2, w_ihr_2, w_hh_2, wsd);
    hipLaunchKernelGGL(conv_x, dim3(256), dim3(256), 0, stream, x, wsd);
    hipLaunchKernelGGL(lstm_persist, dim3(256), dim3(512), 0, stream,
                       b_1, b_2, wsd, out);
}

// Round 18
// 2885.980 us; speedup vs baseline: 1.8170x; 1.0014x over previous
//
#include <hip/hip_runtime.h>
#include <math.h>

typedef unsigned short u16;
typedef unsigned int   u32;
typedef unsigned long long u64;
typedef __bf16 bf16x8 __attribute__((ext_vector_type(8)));
typedef float  f32x4  __attribute__((ext_vector_type(4)));

#define BB 256
#define TT 256
#define HD 256
#define ED 128
#define DEPTH 8      /* h ring slots (= 2*S) */
#define NE 73        /* epochs: 64 + 9 (S=4) */

/* ws layout (u32 units). h rings are u16 arrays, hi and lo separate:
   [0, HRING)          : h-hi ring u16[10][DEPTH][256][256]
   [HRING, 2*HRING)    : h-lo ring u16[10][DEPTH][256][256]
   [CTR_OFF, +512)     : 8 barrier counters (128B padded) + gen bcast @+256
   [GRP_OFF, +640)     : 20 group counters (l*2+bt), 128B padded
   [XPH_OFF, +XP_U32)  : x-hi u16[256][256][8]
   [XPL_OFF, +XP_U32)  : x-lo u16[256][256][8]
   [WT_OFF, ...)       : fragment-ordered bf16 weights (r4-r17 proven)      */
#define HRING   (10 * DEPTH * BB * HD / 2)   /* u32 units per u16 ring */
#define CTR_OFF (2 * HRING)
#define GRP_OFF (CTR_OFF + 512)
#define XP_U32  (BB * TT * 8 / 2)
#define XPH_OFF (GRP_OFF + 640)
#define XPL_OFF (XPH_OFF + XP_U32)
#define WT_OFF  (XPL_OFF + XP_U32)

__constant__ size_t g_woff[10] = {0ul,589824ul,1638400ul,2686976ul,3735552ul,
                                  4784128ul,5177344ul,5439488ul,5701632ul,5963776ul};
__constant__ int g_cb[11] = {0,73728,204800,335872,466944,598016,
                             647168,679936,712704,745472,778240};

__device__ __forceinline__ u16 f2bf_hi(float f) {
    u32 u = __float_as_uint(f);
    u32 r = (u + 0x7FFFu + ((u >> 16) & 1u)) >> 16;
    return (u16)r;
}
__device__ __forceinline__ float bf2f(u16 h) { return __uint_as_float(((u32)h) << 16); }
__device__ __forceinline__ float sigmoidf_(float v) { return 1.0f / (1.0f + expf(-v)); }
__device__ __forceinline__ bf16x8 asbf8(const uint4& u) {
    union { uint4 u; bf16x8 v; } c; c.u = u; return c.v;
}

__global__ __launch_bounds__(256) void zero_state(u32* wsd) {
    const int n = XPH_OFF;
    for (int i = blockIdx.x * blockDim.x + threadIdx.x; i < n; i += gridDim.x * blockDim.x)
        wsd[i] = 0u;
}

__global__ __launch_bounds__(256) void conv_x(const float* __restrict__ x, u32* __restrict__ wsd) {
    u16* xph = (u16*)(wsd + XPH_OFF);
    u16* xpl = (u16*)(wsd + XPL_OFF);
    const int n = BB * TT * 8;
    for (int i = blockIdx.x * blockDim.x + threadIdx.x; i < n; i += gridDim.x * blockDim.x) {
        float v = x[i];
        u16 hi = f2bf_hi(v);
        xph[i] = hi;
        xpl[i] = f2bf_hi(v - bf2f(hi));
    }
}

/* weights -> bf16 hi/lo, MFMA fragment order (identical to rounds 4-17) */
__global__ __launch_bounds__(256) void conv_all(
    const float* __restrict__ w_ih0_1, const float* __restrict__ w_ihr_1,
    const float* __restrict__ w_hh_1,
    const float* __restrict__ w_ih0_2, const float* __restrict__ w_ihr_2,
    const float* __restrict__ w_hh_2,
    u32* __restrict__ wsd)
{
    __bf16* dst0 = (__bf16*)(wsd + WT_OFF);
    const int nch = 778240;
    for (int ci = blockIdx.x * blockDim.x + threadIdx.x; ci < nch;
         ci += gridDim.x * blockDim.x) {
        int l = 0;
        while (ci >= g_cb[l + 1]) ++l;
        int di = ci - g_cb[l];

        const int hd  = (l < 5) ? 256 : 128;
        const int din = (l == 0) ? 32 : ((l < 6) ? 256 : 128);
        const int xw  = (l == 0) ? 8 : din;
        const int Kp  = din + hd;
        const int nk  = Kp >> 5;

        const float *wih, *whh; int wihld, whhld;
        if (l == 0)      { wih = w_ih0_1;                                whh = w_hh_1;
                           wihld = 8;   whhld = 256; }
        else if (l < 5)  { wih = w_ihr_1 + (size_t)(l - 1) * 1024 * 256; whh = w_hh_1 + (size_t)l * 1024 * 256;
                           wihld = 256; whhld = 256; }
        else if (l == 5) { wih = w_ih0_2;                                whh = w_hh_2;
                           wihld = 256; whhld = 128; }
        else             { wih = w_ihr_2 + (size_t)(l - 6) * 512 * 128;  whh = w_hh_2 + (size_t)(l - 5) * 512 * 128;
                           wihld = 128; whhld = 128; }

        int lane = di & 63;
        int rem  = di >> 6;
        int kt   = rem % nk;
        int rem2 = rem / nk;
        int p    = rem2 & 1;
        int g    = (rem2 >> 1) & 3;
        int jt   = rem2 >> 3;
        int r15  = lane & 15, kq = lane >> 4;
        int row  = g * hd + jt * 16 + r15;

        bf16x8 o8;
        #pragma unroll
        for (int e = 0; e < 8; ++e) {
            int k = kt * 32 + kq * 8 + e;
            float v = 0.0f;
            if (k < xw) v = wih[(size_t)row * wihld + k];
            else if (k >= din && k < Kp) v = whh[(size_t)row * whhld + (k - din)];
            __bf16 h = (__bf16)v;
            o8[e] = p ? (__bf16)(v - (float)h) : h;
        }
        *(bf16x8*)(dst0 + g_woff[l] + (size_t)di * 8) = o8;
    }
}

/* persistent S=4 epoch loop with PAIRED input-half fusion:
   per step pair (t, t+1): one dual input-half pass (A fragments read ONCE,
   24 MFMA per 8 ds_reads) + two recurrent halves around the group syncs.
   LDS A-traffic per pair: 2*NKT*8 -> (NKI + 2*NKR)*8 reads (-25%). */
template<int NKI, int NKT, bool ISL0>
__device__ void run_persist(int l, int bid, int xcd, int jt, int bt, int hd, u32 arr7,
    int ng, u32* __restrict__ gflg,
    const float* __restrict__ bias, u32* __restrict__ wsd, u32* __restrict__ ctr,
    float* __restrict__ out, const u16* __restrict__ A_sh)
{
    constexpr int NKR = NKT - NKI;
    constexpr int RS  = (NKR < 4) ? NKR : 4;
    constexpr int RSI = (NKI < 3) ? NKI : 3;

    u16* hhi = (u16*)wsd;
    u16* hlo = (u16*)(wsd + HRING);
    const u16* xph = (const u16*)(wsd + XPH_OFF);
    const u16* xpl = (const u16*)(wsd + XPL_OFF);

    const int tid  = threadIdx.x;
    const int lane = tid & 63;
    const int wv   = tid >> 6;
    const int r15  = lane & 15;
    const int kqc  = lane >> 4;
    const int brow = bt * 128 + wv * 16 + r15;
    const int j0   = jt * 16 + kqc * 4;

    float bgr[4][4];
    #pragma unroll
    for (int g = 0; g < 4; ++g) {
        float4 v = *(const float4*)&bias[g * hd + j0];
        bgr[g][0] = v.x; bgr[g][1] = v.y; bgr[g][2] = v.z; bgr[g][3] = v.w;
    }

    int offH[4], offL[4];
    #pragma unroll
    for (int g = 0; g < 4; ++g) {
        offH[g] = (g * 2)     * NKT * 512 + lane * 8;
        offL[g] = (g * 2 + 1) * NKT * 512 + lane * 8;
    }

    float4 cv = make_float4(0.f, 0.f, 0.f, 0.f);
    const int lm = (l > 0) ? (l - 1) : 0;

    /* 12 MFMA for one timestep's K=32 slice into ac[] (A freshly read) */
    auto MF12 = [&](int kof, const bf16x8& bh, const bf16x8& bl, f32x4 (&ac)[4]) {
        bf16x8 a0h = *(const bf16x8*)&A_sh[offH[0] + kof];
        bf16x8 a1h = *(const bf16x8*)&A_sh[offH[1] + kof];
        bf16x8 a2h = *(const bf16x8*)&A_sh[offH[2] + kof];
        bf16x8 a3h = *(const bf16x8*)&A_sh[offH[3] + kof];
        bf16x8 a0l = *(const bf16x8*)&A_sh[offL[0] + kof];
        bf16x8 a1l = *(const bf16x8*)&A_sh[offL[1] + kof];
        bf16x8 a2l = *(const bf16x8*)&A_sh[offL[2] + kof];
        bf16x8 a3l = *(const bf16x8*)&A_sh[offL[3] + kof];
        ac[0] = __builtin_amdgcn_mfma_f32_16x16x32_bf16(a0h, bh, ac[0], 0, 0, 0);
        ac[1] = __builtin_amdgcn_mfma_f32_16x16x32_bf16(a1h, bh, ac[1], 0, 0, 0);
        ac[2] = __builtin_amdgcn_mfma_f32_16x16x32_bf16(a2h, bh, ac[2], 0, 0, 0);
        ac[3] = __builtin_amdgcn_mfma_f32_16x16x32_bf16(a3h, bh, ac[3], 0, 0, 0);
        ac[0] = __builtin_amdgcn_mfma_f32_16x16x32_bf16(a0h, bl, ac[0], 0, 0, 0);
        ac[1] = __builtin_amdgcn_mfma_f32_16x16x32_bf16(a1h, bl, ac[1], 0, 0, 0);
        ac[2] = __builtin_amdgcn_mfma_f32_16x16x32_bf16(a2h, bl, ac[2], 0, 0, 0);
        ac[3] = __builtin_amdgcn_mfma_f32_16x16x32_bf16(a3h, bl, ac[3], 0, 0, 0);
        ac[0] = __builtin_amdgcn_mfma_f32_16x16x32_bf16(a0l, bh, ac[0], 0, 0, 0);
        ac[1] = __builtin_amdgcn_mfma_f32_16x16x32_bf16(a1l, bh, ac[1], 0, 0, 0);
        ac[2] = __builtin_amdgcn_mfma_f32_16x16x32_bf16(a2l, bh, ac[2], 0, 0, 0);
        ac[3] = __builtin_amdgcn_mfma_f32_16x16x32_bf16(a3l, bh, ac[3], 0, 0, 0);
    };
    /* 24 MFMA: A fragments read once, applied to both timesteps' B */
    auto MF24 = [&](int kof, const bf16x8& b0h, const bf16x8& b0l,
                    const bf16x8& b1h, const bf16x8& b1l,
                    f32x4 (&a0)[4], f32x4 (&a1)[4]) {
        bf16x8 a0h = *(const bf16x8*)&A_sh[offH[0] + kof];
        bf16x8 a1hh = *(const bf16x8*)&A_sh[offH[1] + kof];
        bf16x8 a2h = *(const bf16x8*)&A_sh[offH[2] + kof];
        bf16x8 a3h = *(const bf16x8*)&A_sh[offH[3] + kof];
        bf16x8 a0l = *(const bf16x8*)&A_sh[offL[0] + kof];
        bf16x8 a1l = *(const bf16x8*)&A_sh[offL[1] + kof];
        bf16x8 a2l = *(const bf16x8*)&A_sh[offL[2] + kof];
        bf16x8 a3l = *(const bf16x8*)&A_sh[offL[3] + kof];
        a0[0] = __builtin_amdgcn_mfma_f32_16x16x32_bf16(a0h,  b0h, a0[0], 0, 0, 0);
        a1[0] = __builtin_amdgcn_mfma_f32_16x16x32_bf16(a0h,  b1h, a1[0], 0, 0, 0);
        a0[1] = __builtin_amdgcn_mfma_f32_16x16x32_bf16(a1hh, b0h, a0[1], 0, 0, 0);
        a1[1] = __builtin_amdgcn_mfma_f32_16x16x32_bf16(a1hh, b1h, a1[1], 0, 0, 0);
        a0[2] = __builtin_amdgcn_mfma_f32_16x16x32_bf16(a2h,  b0h, a0[2], 0, 0, 0);
        a1[2] = __builtin_amdgcn_mfma_f32_16x16x32_bf16(a2h,  b1h, a1[2], 0, 0, 0);
        a0[3] = __builtin_amdgcn_mfma_f32_16x16x32_bf16(a3h,  b0h, a0[3], 0, 0, 0);
        a1[3] = __builtin_amdgcn_mfma_f32_16x16x32_bf16(a3h,  b1h, a1[3], 0, 0, 0);
        a0[0] = __builtin_amdgcn_mfma_f32_16x16x32_bf16(a0h,  b0l, a0[0], 0, 0, 0);
        a1[0] = __builtin_amdgcn_mfma_f32_16x16x32_bf16(a0h,  b1l, a1[0], 0, 0, 0);
        a0[1] = __builtin_amdgcn_mfma_f32_16x16x32_bf16(a1hh, b0l, a0[1], 0, 0, 0);
        a1[1] = __builtin_amdgcn_mfma_f32_16x16x32_bf16(a1hh, b1l, a1[1], 0, 0, 0);
        a0[2] = __builtin_amdgcn_mfma_f32_16x16x32_bf16(a2h,  b0l, a0[2], 0, 0, 0);
        a1[2] = __builtin_amdgcn_mfma_f32_16x16x32_bf16(a2h,  b1l, a1[2], 0, 0, 0);
        a0[3] = __builtin_amdgcn_mfma_f32_16x16x32_bf16(a3h,  b0l, a0[3], 0, 0, 0);
        a1[3] = __builtin_amdgcn_mfma_f32_16x16x32_bf16(a3h,  b1l, a1[3], 0, 0, 0);
        a0[0] = __builtin_amdgcn_mfma_f32_16x16x32_bf16(a0l,  b0h, a0[0], 0, 0, 0);
        a1[0] = __builtin_amdgcn_mfma_f32_16x16x32_bf16(a0l,  b1h, a1[0], 0, 0, 0);
        a0[1] = __builtin_amdgcn_mfma_f32_16x16x32_bf16(a1l,  b0h, a0[1], 0, 0, 0);
        a1[1] = __builtin_amdgcn_mfma_f32_16x16x32_bf16(a1l,  b1h, a1[1], 0, 0, 0);
        a0[2] = __builtin_amdgcn_mfma_f32_16x16x32_bf16(a2l,  b0h, a0[2], 0, 0, 0);
        a1[2] = __builtin_amdgcn_mfma_f32_16x16x32_bf16(a2l,  b1h, a1[2], 0, 0, 0);
        a0[3] = __builtin_amdgcn_mfma_f32_16x16x32_bf16(a3l,  b0h, a0[3], 0, 0, 0);
        a1[3] = __builtin_amdgcn_mfma_f32_16x16x32_bf16(a3l,  b1h, a1[3], 0, 0, 0);
    };

    /* dual input-half pass for steps (t0, t0+1) */
    auto DUAL_IN = [&](int t0, f32x4 (&a0)[4], f32x4 (&a1)[4]) {
        if constexpr (ISL0) {
            uint4 h0, l0q, h1, l1q;
            if (kqc == 0) {
                const size_t x0 = ((size_t)brow * TT + t0) * 8;
                const size_t x1 = ((size_t)brow * TT + t0 + 1) * 8;
                h0 = *(const uint4*)(xph + x0); l0q = *(const uint4*)(xpl + x0);
                h1 = *(const uint4*)(xph + x1); l1q = *(const uint4*)(xpl + x1);
            } else {
                h0 = make_uint4(0,0,0,0); l0q = h0; h1 = h0; l1q = h0;
            }
            MF24(0, asbf8(h0), asbf8(l0q), asbf8(h1), asbf8(l1q), a0, a1);
        } else {
            const size_t sIn0 = ((size_t)lm * DEPTH + (t0 & 7)) * (BB * HD);
            const size_t sIn1 = ((size_t)lm * DEPTH + ((t0 + 1) & 7)) * (BB * HD);
            auto ldBI = [&](size_t sIn, int kt, uint4& H4, uint4& L4) {
                const size_t o = sIn + (size_t)brow * HD + kt * 32 + kqc * 8;
                H4 = *(const uint4*)(hhi + o);
                L4 = *(const uint4*)(hlo + o);
            };
            uint4 p0a[RSI], p0b[RSI], p1a[RSI], p1b[RSI];
            #pragma unroll
            for (int i = 0; i < RSI; ++i) {
                ldBI(sIn0, i, p0a[i], p0b[i]);
                ldBI(sIn1, i, p1a[i], p1b[i]);
            }
            #pragma unroll
            for (int kt = 0; kt < NKI; ++kt) {
                bf16x8 b0h = asbf8(p0a[kt % RSI]), b0l = asbf8(p0b[kt % RSI]);
                bf16x8 b1h = asbf8(p1a[kt % RSI]), b1l = asbf8(p1b[kt % RSI]);
                if (kt + RSI < NKI) {
                    ldBI(sIn0, kt + RSI, p0a[kt % RSI], p0b[kt % RSI]);
                    ldBI(sIn1, kt + RSI, p1a[kt % RSI], p1b[kt % RSI]);
                }
                MF24(kt * 512, b0h, b0l, b1h, b1l, a0, a1);
            }
        }
    };

    /* recurrent half + epilogue + h store for step t (acc carries input part) */
    auto REC_STEP = [&](int t, f32x4 (&ac)[4]) {
        const size_t sPrev = ((size_t)l * DEPTH + ((t - 1) & 7)) * (BB * HD);
        const size_t sOut  = ((size_t)l * DEPTH + (t & 7)) * (BB * HD);
        auto ldBR = [&](int kt, uint4& H4, uint4& L4) {
            const size_t o = sPrev + (size_t)brow * HD + (kt - NKI) * 32 + kqc * 8;
            H4 = *(const uint4*)(hhi + o);
            L4 = *(const uint4*)(hlo + o);
        };
        uint4 ra[RS], rb[RS];
        #pragma unroll
        for (int i = 0; i < RS; ++i) ldBR(NKI + i, ra[i], rb[i]);
        #pragma unroll
        for (int kt = NKI; kt < NKT; ++kt) {
            bf16x8 bh = asbf8(ra[(kt - NKI) % RS]), bl = asbf8(rb[(kt - NKI) % RS]);
            if (kt + RS < NKT) ldBR(kt + RS, ra[(kt - NKI) % RS], rb[(kt - NKI) % RS]);
            MF12(kt * 512, bh, bl, ac);
        }

        float4 hv;
        {
            float i_, f_, g_, o_;
            i_ = sigmoidf_(ac[0][0] + bgr[0][0]); f_ = sigmoidf_(ac[1][0] + bgr[1][0]);
            g_ = tanhf   (ac[2][0] + bgr[2][0]); o_ = sigmoidf_(ac[3][0] + bgr[3][0]);
            cv.x = fmaf(f_, cv.x, i_ * g_); hv.x = o_ * tanhf(cv.x);
            i_ = sigmoidf_(ac[0][1] + bgr[0][1]); f_ = sigmoidf_(ac[1][1] + bgr[1][1]);
            g_ = tanhf   (ac[2][1] + bgr[2][1]); o_ = sigmoidf_(ac[3][1] + bgr[3][1]);
            cv.y = fmaf(f_, cv.y, i_ * g_); hv.y = o_ * tanhf(cv.y);
            i_ = sigmoidf_(ac[0][2] + bgr[0][2]); f_ = sigmoidf_(ac[1][2] + bgr[1][2]);
            g_ = tanhf   (ac[2][2] + bgr[2][2]); o_ = sigmoidf_(ac[3][2] + bgr[3][2]);
            cv.z = fmaf(f_, cv.z, i_ * g_); hv.z = o_ * tanhf(cv.z);
            i_ = sigmoidf_(ac[0][3] + bgr[0][3]); f_ = sigmoidf_(ac[1][3] + bgr[1][3]);
            g_ = tanhf   (ac[2][3] + bgr[2][3]); o_ = sigmoidf_(ac[3][3] + bgr[3][3]);
            cv.w = fmaf(f_, cv.w, i_ * g_); hv.w = o_ * tanhf(cv.w);
        }

        u16 h0 = f2bf_hi(hv.x), h1 = f2bf_hi(hv.y), h2 = f2bf_hi(hv.z), h3 = f2bf_hi(hv.w);
        u64 hiP = (u64)h0 | ((u64)h1 << 16) | ((u64)h2 << 32) | ((u64)h3 << 48);
        u64 loP = (u64)f2bf_hi(hv.x - bf2f(h0)) |
                  ((u64)f2bf_hi(hv.y - bf2f(h1)) << 16) |
                  ((u64)f2bf_hi(hv.z - bf2f(h2)) << 32) |
                  ((u64)f2bf_hi(hv.w - bf2f(h3)) << 48);
        const size_t ho = sOut + (size_t)brow * HD + j0;
        __hip_atomic_store((u64*)(hhi + ho), hiP, __ATOMIC_RELAXED, __HIP_MEMORY_SCOPE_AGENT);
        __hip_atomic_store((u64*)(hlo + ho), loP, __ATOMIC_RELAXED, __HIP_MEMORY_SCOPE_AGENT);

        if (l == 9 && t == TT - 1)
            *(float4*)&out[(size_t)brow * ED + j0] = hv;
    };

    auto gpost = [&]() {
        __syncthreads();   /* drain h stores (vmcnt 0) */
        if (tid == 0)
            __hip_atomic_fetch_add(gflg, 1u, __ATOMIC_RELAXED, __HIP_MEMORY_SCOPE_AGENT);
    };
    auto gwait = [&](u32 tg) {
        if (tid == 0) {
            for (int it = 0; it < (1 << 20); ++it) {
                if (__hip_atomic_load(gflg, __ATOMIC_RELAXED,
                                      __HIP_MEMORY_SCOPE_AGENT) >= tg) break;
                __builtin_amdgcn_s_sleep(1);
            }
        }
        __syncthreads();
    };

    for (int E = 0; E < NE; ++E) {
        const int ep = E - l;
        if (ep >= 0 && ep < 64) {
            /* pair 0: steps 4ep, 4ep+1 */
            {
                f32x4 ia0[4], ia1[4];
                #pragma unroll
                for (int g = 0; g < 4; ++g) { ia0[g] = (f32x4){0.f,0.f,0.f,0.f}; ia1[g] = (f32x4){0.f,0.f,0.f,0.f}; }
                DUAL_IN(4 * ep, ia0, ia1);
                REC_STEP(4 * ep, ia0);
                gpost();                                   /* after step 0 */
                gwait((u32)ng * (u32)(3 * ep + 1));
                REC_STEP(4 * ep + 1, ia1);
                gpost();                                   /* after step 1 */
            }
            /* pair 1: steps 4ep+2, 4ep+3 (input pass hoisted before wait) */
            {
                f32x4 ia0[4], ia1[4];
                #pragma unroll
                for (int g = 0; g < 4; ++g) { ia0[g] = (f32x4){0.f,0.f,0.f,0.f}; ia1[g] = (f32x4){0.f,0.f,0.f,0.f}; }
                DUAL_IN(4 * ep + 2, ia0, ia1);
                gwait((u32)ng * (u32)(3 * ep + 2));
                REC_STEP(4 * ep + 2, ia0);
                gpost();                                   /* after step 2 */
                gwait((u32)ng * (u32)(3 * ep + 3));
                REC_STEP(4 * ep + 3, ia1);
            }
        }

        /* ---- global barrier (r14/r17 verbatim) ---- */
        __syncthreads();
        if (tid == 0) {
            __hip_atomic_fetch_add(&ctr[xcd * 32], 1u,
                                   __ATOMIC_RELAXED, __HIP_MEMORY_SCOPE_AGENT);
            const u32 w1 = (u32)(E + 1);
            if (bid == 0) {
                for (int it = 0; it < (1 << 22); ++it) {
                    bool ok = true;
                    #pragma unroll
                    for (int r = 0; r < 8; ++r) {
                        u32 tgt = ((r == 7) ? arr7 : 32u) * w1;
                        ok &= (__hip_atomic_load(&ctr[r * 32], __ATOMIC_RELAXED,
                                                 __HIP_MEMORY_SCOPE_AGENT) >= tgt);
                    }
                    if (ok) break;
                    __builtin_amdgcn_s_sleep(1);
                }
                __hip_atomic_store(&ctr[256], w1, __ATOMIC_RELAXED, __HIP_MEMORY_SCOPE_AGENT);
            } else {
                for (int it = 0; it < (1 << 22); ++it) {
                    if (__hip_atomic_load(&ctr[256], __ATOMIC_RELAXED,
                                          __HIP_MEMORY_SCOPE_AGENT) >= w1) break;
                    __builtin_amdgcn_s_sleep(1);
                }
            }
            __builtin_amdgcn_fence(__ATOMIC_ACQUIRE, "agent");  /* inv, no writeback */
        }
        __syncthreads();
    }
}

/* Grid 256 (16 idle), 512 thr = 8 waves x 16 batches (r10-r17 structure).
   bid%8 = XCD heuristic (correctness placement-agnostic):
     xcd 0-4 : layer = xcd   (16 jt x 2 bt)
     xcd 5   : layers 5,6 ; xcd 6 : layers 7,8 ; xcd 7 : layer 9 (16 blk) */
__global__ __launch_bounds__(512, 2) void lstm_persist(
    const float* __restrict__ b_1, const float* __restrict__ b_2,
    u32* __restrict__ wsd, float* __restrict__ out)
{
    __shared__ __align__(16) u16 A_sh[65536];   /* 128 KiB */

    const int bid = blockIdx.x;
    const int xcd = bid & 7, slot = bid >> 3;
    int l, jt, bt;
    if (xcd < 5)      { l = xcd;               bt = slot >> 4;        jt = slot & 15; }
    else if (xcd == 5){ l = 5 + (slot >> 4);   bt = (slot >> 3) & 1;  jt = slot & 7; }
    else if (xcd == 6){ l = 7 + (slot >> 4);   bt = (slot >> 3) & 1;  jt = slot & 7; }
    else              { if (slot >= 16) return; l = 9; bt = slot >> 3; jt = slot & 7; }

    const int hd  = (l < 5) ? 256 : 128;
    const int din = (l == 0) ? 32 : ((l < 6) ? 256 : 128);
    const int nk  = (din + hd) >> 5;
    const float* bias = (l < 5) ? (b_1 + l * 1024) : (b_2 + (l - 5) * 512);

    u32* ctr  = wsd + CTR_OFF;
    u32* gflg = wsd + GRP_OFF + (size_t)(l * 2 + bt) * 32;
    const u16* wt = (const u16*)(wsd + WT_OFF);

    const int ng = (l < 5) ? 16 : 8;   /* blocks in this (l,bt) group */

    /* one-time: copy this block's fragment-ordered weight slice into LDS */
    {
        const uint4* src = (const uint4*)(wt + g_woff[l] + (size_t)jt * 8 * nk * 512);
        uint4* dst = (uint4*)A_sh;
        const int n4 = nk * 512;
        for (int i = threadIdx.x; i < n4; i += 512) dst[i] = src[i];
    }
    __syncthreads();

    if (l == 0)
        run_persist<1, 9, true >(l, bid, xcd, jt, bt, hd, 16u, ng, gflg, bias, wsd, ctr, out, A_sh);
    else if (l < 5)
        run_persist<8, 16, false>(l, bid, xcd, jt, bt, hd, 16u, ng, gflg, bias, wsd, ctr, out, A_sh);
    else if (l == 5)
        run_persist<8, 12, false>(l, bid, xcd, jt, bt, hd, 16u, ng, gflg, bias, wsd, ctr, out, A_sh);
    else
        run_persist<4, 8, false>(l, bid, xcd, jt, bt, hd, 16u, ng, gflg, bias, wsd, ctr, out, A_sh);
}

extern "C" void kernel_launch(void* const* d_in, const int* in_sizes, int n_in,
                              void* d_out, int out_size, void* d_ws, size_t ws_size,
                              hipStream_t stream) {
    const float* x       = (const float*)d_in[0];
    const float* w_ih0_1 = (const float*)d_in[1];
    const float* w_ihr_1 = (const float*)d_in[2];
    const float* w_hh_1  = (const float*)d_in[3];
    const float* b_1     = (const float*)d_in[4];
    const float* w_ih0_2 = (const float*)d_in[5];
    const float* w_ihr_2 = (const float*)d_in[6];
    const float* w_hh_2  = (const float*)d_in[7];
    const float* b_2     = (const float*)d_in[8];
    u32*   wsd = (u32*)d_ws;
    float* out = (float*)d_out;

    hipLaunchKernelGGL(zero_state, dim3(1024), dim3(256), 0, stream, wsd);
    hipLaunchKernelGGL(conv_all, dim3(1024), dim3(256), 0, stream,
                       w_ih0_1, w_ihr_1, w_hh_1, w_ih0_2, w_ihr_2, w_hh_2, wsd);
    hipLaunchKernelGGL(conv_x, dim3(256), dim3(256), 0, stream, x, wsd);
    hipLaunchKernelGGL(lstm_persist, dim3(256), dim3(512), 0, stream,
                       b_1, b_2, wsd, out);
}